// Round 1
// baseline (821.280 us; speedup 1.0000x reference)
//
#include <hip/hip_runtime.h>
#include <hip/hip_bf16.h>

typedef __bf16 bf16x8 __attribute__((ext_vector_type(8)));
typedef float  f32x4  __attribute__((ext_vector_type(4)));

constexpr int D = 128;   // embedding dim
constexpr int P = 256;   // prototypes
constexpr float EPS = 1e-12f;

// Each block: 4 waves. Wave w owns columns [w*64, w*64+64) (4 ntiles of 16).
// B (prototypes) fragments live in registers, loaded once per block.
// Grid-stride loop over 16-row tiles of embeddings; all 4 waves share the
// same 16 rows (A loads hit L1 for 3 of 4 waves).
__global__ __launch_bounds__(256, 3)
void proto_dist_kernel(const float* __restrict__ emb,
                       const float* __restrict__ proto,
                       float* __restrict__ out,
                       int N, int ntiles)
{
    const int lane = threadIdx.x & 63;
    const int wave = threadIdx.x >> 6;
    const int quad = lane >> 4;
    const int l15  = lane & 15;
    const int colbase = wave * 64;

    // ---- Load B fragments (bf16) + per-column squared norms p2 ----
    // B-operand layout (16x16x32): lane holds B[k = quad*8+j][n = lane&15],
    // i.e. proto[n][k0..k0+7] -> 8 consecutive fp32 -> 2x float4.
    bf16x8 bfrag[4][4];   // [ntile][kstep]
    float  p2[4];
    #pragma unroll
    for (int t = 0; t < 4; ++t) {
        const int n = colbase + t * 16 + l15;
        const float* src = proto + n * D + quad * 8;
        float s = 0.f;
        #pragma unroll
        for (int ks = 0; ks < 4; ++ks) {
            f32x4 lo = *(const f32x4*)(src + ks * 32);
            f32x4 hi = *(const f32x4*)(src + ks * 32 + 4);
            s += lo.x*lo.x + lo.y*lo.y + lo.z*lo.z + lo.w*lo.w;
            s += hi.x*hi.x + hi.y*hi.y + hi.z*hi.z + hi.w*hi.w;
            bf16x8 f;
            f[0]=(__bf16)lo.x; f[1]=(__bf16)lo.y; f[2]=(__bf16)lo.z; f[3]=(__bf16)lo.w;
            f[4]=(__bf16)hi.x; f[5]=(__bf16)hi.y; f[6]=(__bf16)hi.z; f[7]=(__bf16)hi.w;
            bfrag[t][ks] = f;
        }
        // p2 partial covers this lane's 32 k-values; sum the 4 quads.
        s += __shfl_xor(s, 16);
        s += __shfl_xor(s, 32);
        p2[t] = s;   // full ||proto[col]||^2, col = colbase + t*16 + l15
    }

    for (int tile = blockIdx.x; tile < ntiles; tile += gridDim.x) {
        const int row0 = tile * 16;
        int rowA = row0 + l15;
        if (rowA > N - 1) rowA = N - 1;               // clamp (N%16==0 here)
        const float* arow = emb + (long)rowA * D + quad * 8;

        // ---- A fragments + e2 (exact fp32) ----
        bf16x8 afrag[4];
        float e2p = 0.f;
        #pragma unroll
        for (int ks = 0; ks < 4; ++ks) {
            f32x4 lo = __builtin_nontemporal_load((const f32x4*)(arow + ks * 32));
            f32x4 hi = __builtin_nontemporal_load((const f32x4*)(arow + ks * 32 + 4));
            e2p += lo.x*lo.x + lo.y*lo.y + lo.z*lo.z + lo.w*lo.w;
            e2p += hi.x*hi.x + hi.y*hi.y + hi.z*hi.z + hi.w*hi.w;
            bf16x8 f;
            f[0]=(__bf16)lo.x; f[1]=(__bf16)lo.y; f[2]=(__bf16)lo.z; f[3]=(__bf16)lo.w;
            f[4]=(__bf16)hi.x; f[5]=(__bf16)hi.y; f[6]=(__bf16)hi.z; f[7]=(__bf16)hi.w;
            afrag[ks] = f;
        }
        float e2full = e2p;
        e2full += __shfl_xor(e2full, 16);
        e2full += __shfl_xor(e2full, 32);   // full ||emb[row0 + (lane&15)]||^2

        // ---- MFMA cross terms: acc[t] = emb_tile x proto_cols(t) ----
        f32x4 acc[4];
        const f32x4 zero = {0.f, 0.f, 0.f, 0.f};
        #pragma unroll
        for (int t = 0; t < 4; ++t) acc[t] = zero;
        #pragma unroll
        for (int ks = 0; ks < 4; ++ks) {
            #pragma unroll
            for (int t = 0; t < 4; ++t) {
                acc[t] = __builtin_amdgcn_mfma_f32_16x16x32_bf16(
                    afrag[ks], bfrag[t][ks], acc[t], 0, 0, 0);
            }
        }

        // ---- Epilogue: d = -sqrt(max(e2 + p2 - 2*cross, EPS)) ----
        // C/D layout: col = lane&15, row = quad*4 + reg.
        float e2r[4];
        #pragma unroll
        for (int r = 0; r < 4; ++r)
            e2r[r] = __shfl(e2full, quad * 4 + r);

        #pragma unroll
        for (int t = 0; t < 4; ++t) {
            const int col = colbase + t * 16 + l15;
            #pragma unroll
            for (int r = 0; r < 4; ++r) {
                const int grow = row0 + quad * 4 + r;
                if (grow < N) {
                    float d2 = fmaf(-2.f, acc[t][r], e2r[r] + p2[t]);
                    d2 = fmaxf(d2, EPS);
                    __builtin_nontemporal_store(-__builtin_sqrtf(d2),
                                                out + (long)grow * P + col);
                }
            }
        }
    }
}

extern "C" void kernel_launch(void* const* d_in, const int* in_sizes, int n_in,
                              void* d_out, int out_size, void* d_ws, size_t ws_size,
                              hipStream_t stream)
{
    const float* emb   = (const float*)d_in[0];
    const float* proto = (const float*)d_in[1];
    float* out = (float*)d_out;

    const int N = in_sizes[0] / D;          // 500000
    const int ntiles = (N + 15) / 16;       // 31250
    int blocks = ntiles < 1024 ? ntiles : 1024;

    proto_dist_kernel<<<dim3(blocks), dim3(256), 0, stream>>>(emb, proto, out, N, ntiles);
}